// Round 1
// baseline (149.809 us; speedup 1.0000x reference)
//
#include <hip/hip_runtime.h>

// FOFE encoding: out[row, :] = sum_k alpha^(L-1-k) * onehot(char_ids[row, k])
// rows = B*W = 131072, L = 20, VOCAB = 256. Output fp32, 128 MiB -> write-BW bound.
//
// Strategy: one wave (64 lanes) per row. Each wave owns a 256-float (1 KiB) LDS
// slice. Phases per row: (1) zero slice with ds_write_b128, (2) lanes 0..19
// ds_add_f32 their precomputed power into lds[id] (handles duplicate ids exactly
// like the reference scatter-add), (3) read back float4 per lane and do a fully
// coalesced 1 KiB global_store_dwordx4 burst per row.
// Grid-stride loop amortizes the one-time power computation; __syncthreads()
// between phases (uniform trip count across the block) enforces LDS ordering.

constexpr int L = 20;
constexpr int VOCAB = 256;
constexpr int BLOCK = 256;           // 4 waves per block
constexpr int GRID = 2048;           // 8 blocks/CU on 256 CUs; 16 rows per wave

__global__ __launch_bounds__(BLOCK) void fofe_kernel(
    const int* __restrict__ char_ids,
    const float* __restrict__ alpha_ptr,
    float* __restrict__ out,
    int n_rows)
{
    __shared__ float sm[(BLOCK / 64) * VOCAB];   // 4 KiB: one 256-float slice per wave

    const int lane            = threadIdx.x & 63;
    const int wave            = threadIdx.x >> 6;
    const int waves_per_block = BLOCK >> 6;
    const int wave_id         = blockIdx.x * waves_per_block + wave;
    const int total_waves     = gridDim.x * waves_per_block;

    const float alpha = *alpha_ptr;

    // pw = alpha^(L-1-lane) for lane < L (lane k holds the power for char k).
    // Uniform loop, computed once per thread; matches reference alpha**arange
    // to ~1 ulp/step (<= ~1e-6 abs error, values <= 1).
    float pw = 1.0f;
    {
        float cur = 1.0f;
        #pragma unroll
        for (int e = 0; e < L; ++e) {
            if (lane == (L - 1) - e) pw = cur;
            cur *= alpha;
        }
    }

    float*  smw = sm + wave * VOCAB;
    float4* sm4 = (float4*)smw;
    float4* out4 = (float4*)out;

    const int iters = (n_rows + total_waves - 1) / total_waves;
    for (int it = 0; it < iters; ++it) {
        const int  row    = wave_id + it * total_waves;
        const bool active = row < n_rows;

        // Phase 1: zero this wave's LDS slice (1 ds_write_b128 per lane).
        if (active) sm4[lane] = make_float4(0.f, 0.f, 0.f, 0.f);
        __syncthreads();

        // Phase 2: scatter-add. Lanes 0..19 read 80 contiguous bytes (one
        // coalesced transaction) and ds_add_f32 into lds[id].
        if (active && lane < L) {
            const int id = char_ids[(size_t)row * L + lane];
            atomicAdd(&smw[id], pw);
        }
        __syncthreads();

        // Phase 3: read back and stream out 1 KiB per row, fully coalesced.
        if (active) {
            out4[(size_t)row * (VOCAB / 4) + lane] = sm4[lane];
        }
        __syncthreads();
    }
}

extern "C" void kernel_launch(void* const* d_in, const int* in_sizes, int n_in,
                              void* d_out, int out_size, void* d_ws, size_t ws_size,
                              hipStream_t stream) {
    const int*   char_ids = (const int*)d_in[0];
    const float* alpha    = (const float*)d_in[1];
    float*       out      = (float*)d_out;
    const int    n_rows   = in_sizes[0] / L;   // 131072

    fofe_kernel<<<GRID, BLOCK, 0, stream>>>(char_ids, alpha, out, n_rows);
}

// Round 4
// 146.991 us; speedup vs baseline: 1.0192x; 1.0192x over previous
//
#include <hip/hip_runtime.h>

// FOFE encoding: out[row, :] = sum_k alpha^(L-1-k) * onehot(char_ids[row, k])
// rows = B*W = 131072, L = 20, VOCAB = 256. Output fp32 = 128 MiB -> write-BW bound.
//
// R1 post-mortem: 3x __syncthreads per row compiled to `s_waitcnt vmcnt(0);
// s_barrier` per iteration, draining every 1 KiB store to ack before the next
// row -> in-flight writes capped at 1 KiB/wave -> 0.92 TB/s (149.8 us).
// Fix: LDS slices are WAVE-PRIVATE, so no block barrier is needed -- a wave's
// DS ops execute in issue order; only compiler code-motion fences are needed.
// Also: 2 rows per wave per iteration (2 KiB stores in flight, 160 B
// contiguous id load across lanes 0..39) and software prefetch of the next
// iteration's ids so the HBM id-load latency hides under the store phase.
//
// R2/R3 returned "container failed twice" (same error as the R0 stub, so
// likely infra); only change this round: wave_barrier() fences replaced with
// asm volatile memory clobbers (zero instructions, stronger compiler-ordering
// semantics, nothing exotic for the toolchain).

constexpr int L     = 20;
constexpr int VOCAB = 256;
constexpr int BLOCK = 256;            // 4 waves per block
constexpr int GRID  = 2048;           // 8 blocks/CU -> 32 waves/CU resident
constexpr int R     = 2;              // rows per wave per iteration

__global__ __launch_bounds__(BLOCK) void fofe_kernel(
    const int* __restrict__ char_ids,
    const float* __restrict__ alpha_ptr,
    float* __restrict__ out,
    int n_rows)
{
    // 4 waves x 2 slices x 1 KiB = 8 KiB per block
    __shared__ float sm[(BLOCK / 64) * R * VOCAB];

    const int lane        = threadIdx.x & 63;
    const int wave        = threadIdx.x >> 6;
    const int wave_id     = blockIdx.x * (BLOCK >> 6) + wave;
    const int total_waves = gridDim.x * (BLOCK >> 6);

    const float alpha = *alpha_ptr;

    // Lane l (l < R*L = 40) scatters char (l % L) of row (pair*R + l/L).
    const int sub = (lane >= L) ? 1 : 0;
    const int ch  = lane - sub * L;

    // pw = alpha^(L-1-ch). Same fp sequence as reference's alpha**arange
    // (repeated multiply), <= ~1e-6 abs deviation.
    float pw = 1.0f;
    {
        float cur = 1.0f;
        #pragma unroll
        for (int e = 0; e < L; ++e) {
            if (ch == (L - 1) - e) pw = cur;   // never true for lanes >= 40 (ch >= 20)
            cur *= alpha;
        }
    }

    float*  smw  = sm + wave * (R * VOCAB);
    float4* sm4  = (float4*)smw;               // 2*64 float4 per wave
    float4* out4 = (float4*)out;

    const int n_pairs = n_rows / R;            // 65536; 8 pairs per wave
    const bool scat   = lane < R * L;

    // Prime the id pipeline: load this wave's first pair of rows.
    int id_cur = 0;
    if (wave_id < n_pairs && scat)
        id_cur = char_ids[(size_t)wave_id * (R * L) + lane];

    for (int pair = wave_id; pair < n_pairs; pair += total_waves) {
        // Phase 1: zero both slices (2x ds_write_b128 per lane).
        sm4[lane]      = make_float4(0.f, 0.f, 0.f, 0.f);
        sm4[lane + 64] = make_float4(0.f, 0.f, 0.f, 0.f);

        // Prefetch next iteration's ids (independent of LDS; overlaps phases 2-3).
        const int next_pair = pair + total_waves;
        int id_next = 0;
        if (next_pair < n_pairs && scat)
            id_next = char_ids[(size_t)next_pair * (R * L) + lane];

        asm volatile("" ::: "memory");         // order: zeros before atomics (0 insts)

        // Phase 2: scatter-add into this wave's private slices.
        if (scat)
            atomicAdd(&smw[sub * VOCAB + id_cur], pw);

        asm volatile("" ::: "memory");         // order: atomics before readback

        // Phase 3: read back and stream out 2 KiB, fully coalesced.
        const float4 v0 = sm4[lane];
        const float4 v1 = sm4[lane + 64];
        const size_t o  = (size_t)pair * (R * VOCAB / 4);
        out4[o + lane]      = v0;
        out4[o + 64 + lane] = v1;

        id_cur = id_next;
        asm volatile("" ::: "memory");         // order: readback before next zero
    }
}

extern "C" void kernel_launch(void* const* d_in, const int* in_sizes, int n_in,
                              void* d_out, int out_size, void* d_ws, size_t ws_size,
                              hipStream_t stream) {
    const int*   char_ids = (const int*)d_in[0];
    const float* alpha    = (const float*)d_in[1];
    float*       out      = (float*)d_out;
    const int    n_rows   = in_sizes[0] / L;   // 131072

    fofe_kernel<<<GRID, BLOCK, 0, stream>>>(char_ids, alpha, out, n_rows);
}

// Round 5
// 140.958 us; speedup vs baseline: 1.0628x; 1.0428x over previous
//
#include <hip/hip_runtime.h>

// FOFE encoding: out[row, :] = sum_k alpha^(L-1-k) * onehot(char_ids[row, k])
// rows = B*W = 131072, L = 20, VOCAB = 256. Output fp32 = 128 MiB -> write-BW bound.
//
// R4 post-mortem: dur_us (147us) includes ~100us of harness re-poison; the
// kernel itself is ~45us (absent from top-5 dispatches which are all 78us
// fills). Barrier removal was NEUTRAL because the in-loop id prefetch load
// still forced a per-iteration s_waitcnt vmcnt(N) targeting an op older than
// the just-issued stores -- vmcnt is a single load+store queue on CDNA, so
// that wait kept draining the write stream, capping in-flight writes exactly
// like the old s_barrier did.
//
// R5 fix: NO vmem loads inside the store loop. Each wave owns 8 consecutive
// pairs (16 rows, 16 KiB contiguous output). All 8 ids/lane are loaded
// up-front (8 independent global_load_dword, waits only target loads that
// predate any store), then a fully-unrolled loop does LDS zero/atomic/read +
// 2 global_store_dwordx4 per pair with zero vmem waits -- stores stream
// freely, paced only by the ~250-cyc wave-private LDS chain.

constexpr int L     = 20;
constexpr int VOCAB = 256;
constexpr int BLOCK = 256;            // 4 waves per block
constexpr int GRID  = 2048;           // 8 blocks/CU -> 32 waves/CU resident
constexpr int R     = 2;              // rows per pair
constexpr int PPW   = 8;              // pairs per wave: 8192 waves * 8 * 2 = 131072 rows

__global__ __launch_bounds__(BLOCK) void fofe_kernel(
    const int* __restrict__ char_ids,
    const float* __restrict__ alpha_ptr,
    float* __restrict__ out,
    int n_rows)
{
    // 4 waves x 2 slices x 1 KiB = 8 KiB per block
    __shared__ float sm[(BLOCK / 64) * R * VOCAB];

    const int lane        = threadIdx.x & 63;
    const int wave        = threadIdx.x >> 6;
    const int wave_id     = blockIdx.x * (BLOCK >> 6) + wave;
    const int total_waves = gridDim.x * (BLOCK >> 6);

    const float alpha = *alpha_ptr;

    // Lane l (l < R*L = 40) scatters char (l % L) of row (pair*R + l/L).
    const int sub = (lane >= L) ? 1 : 0;
    const int ch  = lane - sub * L;

    // pw = alpha^(L-1-ch). Same fp sequence as reference's alpha**arange
    // (repeated multiply), <= ~1e-6 abs deviation.
    float pw = 1.0f;
    {
        float cur = 1.0f;
        #pragma unroll
        for (int e = 0; e < L; ++e) {
            if (ch == (L - 1) - e) pw = cur;   // never true for lanes >= 40
            cur *= alpha;
        }
    }

    float*  smw  = sm + wave * (R * VOCAB);
    float4* sm4  = (float4*)smw;               // 2*64 float4 per wave
    float4* out4 = (float4*)out;

    const int n_pairs = n_rows / R;            // 65536
    const bool scat   = lane < R * L;

    // Blocked assignment: wave owns pairs [wave_id*PPW, wave_id*PPW+PPW).
    // Outer grid-stride loop runs exactly once at the bench shape; kept for
    // generality.
    for (int base = wave_id * PPW; base < n_pairs; base += total_waves * PPW) {

        // ---- Up-front id loads: the ONLY vmem reads. 8 independent
        // global_load_dword; each wait targets only these loads, and at first
        // use zero stores have been issued, so no wait ever drains a store.
        int id[PPW];
        #pragma unroll
        for (int i = 0; i < PPW; ++i) {
            const int pair = base + i;
            id[i] = (scat && pair < n_pairs)
                        ? char_ids[(size_t)pair * (R * L) + lane] : 0;
        }

        // ---- Store loop: LDS ops + stores only, no vmem loads, no waits on
        // the write stream. Fully unrolled so vmcnt bookkeeping is static.
        #pragma unroll
        for (int i = 0; i < PPW; ++i) {
            const int pair = base + i;
            if (pair < n_pairs) {              // wave-uniform condition
                // zero this wave's two slices (2x ds_write_b128 per lane)
                sm4[lane]      = make_float4(0.f, 0.f, 0.f, 0.f);
                sm4[lane + 64] = make_float4(0.f, 0.f, 0.f, 0.f);
                asm volatile("" ::: "memory"); // zeros before atomics

                if (scat)
                    atomicAdd(&smw[sub * VOCAB + id[i]], pw);
                asm volatile("" ::: "memory"); // atomics before readback

                const float4 v0 = sm4[lane];
                const float4 v1 = sm4[lane + 64];
                const size_t o  = (size_t)pair * (R * VOCAB / 4);
                out4[o + lane]      = v0;
                out4[o + 64 + lane] = v1;
                asm volatile("" ::: "memory"); // readback before next zero
            }
        }
    }
}

extern "C" void kernel_launch(void* const* d_in, const int* in_sizes, int n_in,
                              void* d_out, int out_size, void* d_ws, size_t ws_size,
                              hipStream_t stream) {
    const int*   char_ids = (const int*)d_in[0];
    const float* alpha    = (const float*)d_in[1];
    float*       out      = (float*)d_out;
    const int    n_rows   = in_sizes[0] / L;   // 131072

    fofe_kernel<<<GRID, BLOCK, 0, stream>>>(char_ids, alpha, out, n_rows);
}